// Round 10
// baseline (350.499 us; speedup 1.0000x reference)
//
#include <hip/hip_runtime.h>
#include <hip/hip_bf16.h>
#include <cstddef>

// EGNN layer. Round 10: occupancy un-cap + packed bf16 converts.
//  - edge/node __launch_bounds__(256,4): measured occupancy tracked the
//    launch-bounds promise all session (r5 (256,3)->30%, r6-9 (256,2)->21%);
//    VGPR/LDS allow 4 blocks/CU. ~45% of edge cycles are stalls -> more waves.
//  - f32->bf16 via __float22bfloat162_rn (v_cvt_pk_bf16_f32 on gfx950),
//    replacing 3-op manual RNE in all hot paths.
//  - structure otherwise = round 9 (fused layer1 MFMA, pk_add_bf16 tot_msg).
//
// MFMA fragment layouts (gfx950, 16x16x32 bf16, verified learn_hip m89/m91):
//   A: lane holds A[m=lane&15][k=(lane>>4)*8 + j], j=0..7
//   B: lane holds B[k=(lane>>4)*8 + j][n=lane&15]
//   C/D: lane reg r holds D[row=(lane>>4)*4+r][col=lane&15]

#define N_NODES 50000
#define M_EDGES 800000

typedef __attribute__((ext_vector_type(8))) short bf16x8;
typedef __attribute__((ext_vector_type(4))) short bf16x4;
typedef __attribute__((ext_vector_type(2))) short bf16x2;
typedef __attribute__((ext_vector_type(4))) float f32x4;

// fragment ids (each frag = 64 lanes x 8 shorts = 512 shorts)
#define FR_WA   0
#define FR_WB   8
#define FR_W1C  16
#define FR_W2   20
#define FR_WC1  28
#define FR_WN1  36
#define FR_WN2  52
#define FR_TOTAL 60

__device__ __forceinline__ float silu_f(float v) {
    return v / (1.0f + __expf(-v));
}

__device__ __forceinline__ short f2bf(float f) {   // RNE float->bf16 (prep only)
    union { float f; unsigned u; } v; v.f = f;
    unsigned r = v.u + 0x7fffu + ((v.u >> 16) & 1u);
    return (short)(r >> 16);
}

// packed RNE f32x2 -> bf16x2 (v_cvt_pk_bf16_f32 on gfx950)
__device__ __forceinline__ unsigned pk2(float a, float b) {
    union { __hip_bfloat162 v; unsigned u; } c;
    c.v = __float22bfloat162_rn(make_float2(a, b));
    return c.u;
}

__device__ __forceinline__ void atomic_pk_add_bf16(unsigned short* p, unsigned int packed) {
#if __has_builtin(__builtin_amdgcn_global_atomic_fadd_v2bf16)
    typedef bf16x2 __attribute__((address_space(1))) gbf16x2;
    union { unsigned int u; bf16x2 v; } c; c.u = packed;
    __builtin_amdgcn_global_atomic_fadd_v2bf16((gbf16x2*)(unsigned long long)p, c.v);
#else
    asm volatile("global_atomic_pk_add_bf16 %0, %1, off"
                 :: "v"((unsigned long long)p), "v"(packed) : "memory");
#endif
}

#define LDS_FENCE() __asm__ volatile("" ::: "memory")

__device__ __forceinline__ bf16x8 load_frag(const unsigned short* wfrag, int f, int lane) {
    return *(const bf16x8*)(wfrag + (size_t)f * 512 + lane * 8);
}

// ---------------------------------------------------------------- K0: prep
#define PREP_W   (FR_TOTAL * 64)
#define PREP_H   (N_NODES * 8)
#define PREP_ZM  (N_NODES * 8)
#define PREP_ZF  (N_NODES)
#define PREP_TOTAL (PREP_W + PREP_H + PREP_ZM + PREP_ZF)

__global__ __launch_bounds__(256) void prep_kernel(
    const float* __restrict__ w1e, const float* __restrict__ w2e,
    const float* __restrict__ wc1, const float* __restrict__ wn1,
    const float* __restrict__ wn2, const float* __restrict__ h,
    unsigned short* __restrict__ wfrag, unsigned short* __restrict__ h_bf,
    unsigned short* __restrict__ tot_msg, float* __restrict__ totf4)
{
    for (int gid = blockIdx.x * 256 + threadIdx.x; gid < PREP_TOTAL;
         gid += gridDim.x * 256) {
        if (gid < PREP_W) {
            const int frag = gid >> 6, lane = gid & 63;
            const int l15 = lane & 15, l4 = lane >> 4;
            const float* src; int k0, t; bool pad16 = false;
            if (frag < FR_WB)        { const int f = frag - FR_WA;  t = f >> 1; src = w1e; k0 = 1 + (f & 1) * 32; }
            else if (frag < FR_W1C)  { const int f = frag - FR_WB;  t = f >> 1; src = w1e; k0 = 65 + (f & 1) * 32; }
            else if (frag < FR_W2)   { t = frag - FR_W1C; src = w1e; k0 = 129; pad16 = true; }
            else if (frag < FR_WC1)  { const int f = frag - FR_W2;  t = f >> 1; src = w2e; k0 = (f & 1) * 32; }
            else if (frag < FR_WN1)  { const int f = frag - FR_WC1; t = f >> 1; src = wc1; k0 = (f & 1) * 32; }
            else if (frag < FR_WN2)  { const int f = frag - FR_WN1; t = f >> 2; src = wn1; k0 = (f & 3) * 32; }
            else                     { const int f = frag - FR_WN2; t = f >> 1; src = wn2; k0 = (f & 1) * 32; }
            const int col = t * 16 + l15;
            bf16x8 v;
            #pragma unroll
            for (int j = 0; j < 8; ++j) {
                const int k = l4 * 8 + j;
                const float xv = (pad16 && k >= 16) ? 0.f : src[(size_t)(k0 + k) * 64 + col];
                v[j] = f2bf(xv);
            }
            *(bf16x8*)(wfrag + (size_t)frag * 512 + lane * 8) = v;
        } else if (gid < PREP_W + PREP_H) {
            const int j = gid - PREP_W;
            const float* src = h + (size_t)j * 8;
            const f32x4 f0 = *(const f32x4*)src;
            const f32x4 f1 = *(const f32x4*)(src + 4);
            uint4 v;
            v.x = pk2(f0[0], f0[1]); v.y = pk2(f0[2], f0[3]);
            v.z = pk2(f1[0], f1[1]); v.w = pk2(f1[2], f1[3]);
            *(uint4*)(h_bf + (size_t)j * 8) = v;
        } else if (gid < PREP_W + PREP_H + PREP_ZM) {
            const int j = gid - PREP_W - PREP_H;
            ((uint4*)tot_msg)[j] = make_uint4(0u, 0u, 0u, 0u);
        } else {
            const int j = gid - PREP_W - PREP_H - PREP_ZM;
            const f32x4 zf = {0.f, 0.f, 0.f, 0.f};
            ((f32x4*)totf4)[j] = zf;
        }
    }
}

// ---------------------------------------------------------------- K2: edges
__global__ __launch_bounds__(256, 4) void edge_kernel(
    const float* __restrict__ x, const float* __restrict__ edge_fea,
    const float* __restrict__ w1e, const float* __restrict__ b1e,
    const float* __restrict__ b2e, const float* __restrict__ bc1,
    const float* __restrict__ wc2, const float* __restrict__ bc2,
    const int* __restrict__ row, const int* __restrict__ col,
    const unsigned short* __restrict__ h_bf,
    const unsigned short* __restrict__ wfrag,
    unsigned short* __restrict__ tot_msg, float* __restrict__ totf4)
{
    __shared__ __align__(16) short wlds[16 * 512];   // w2 (8) + wc1 (8) frags
    __shared__ __align__(16) short u_s[4][16 * 72];  // per-wave activation tile
    __shared__ f32x4 cst_s[5][16];                   // b1,w1r0,b2,bc1,wc2

    const int tid  = threadIdx.x;
    const int lane = tid & 63;
    const int wv   = __builtin_amdgcn_readfirstlane(tid >> 6);
    const int l15  = lane & 15;
    const int l4   = lane >> 4;

    {   // stage w2+wc1 frags into LDS (16KB)
        const uint4* src = (const uint4*)(wfrag + (size_t)FR_W2 * 512);
        uint4* dst = (uint4*)wlds;
        for (int i = tid; i < 1024; i += 256) dst[i] = src[i];
    }
    if (tid < 16)       cst_s[0][tid]      = *(const f32x4*)(b1e + tid * 4);
    else if (tid < 32)  cst_s[1][tid - 16] = *(const f32x4*)(w1e + (tid - 16) * 4);
    else if (tid < 48)  cst_s[2][tid - 32] = *(const f32x4*)(b2e + (tid - 32) * 4);
    else if (tid < 64)  cst_s[3][tid - 48] = *(const f32x4*)(bc1 + (tid - 48) * 4);
    else if (tid < 80)  cst_s[4][tid - 64] = *(const f32x4*)(wc2 + (tid - 64) * 4);

    // layer-1 weight frags in registers
    bf16x8 bw1cf[4], waf[4][2], wbf[4][2];
    #pragma unroll
    for (int t = 0; t < 4; ++t) {
        bw1cf[t] = load_frag(wfrag, FR_W1C + t, lane);
        #pragma unroll
        for (int s = 0; s < 2; ++s) {
            waf[t][s] = load_frag(wfrag, FR_WA + t * 2 + s, lane);
            wbf[t][s] = load_frag(wfrag, FR_WB + t * 2 + s, lane);
        }
    }
    const float bc2v = bc2[0];
    __syncthreads();

    short* const us = &u_s[wv][0];
    const f32x4 zf = {0.f, 0.f, 0.f, 0.f};

    // ---- pipelined group loop
    const int groups = M_EDGES / 64;     // 12500
    const int gstep  = gridDim.x;
    int g = blockIdx.x;

    int   cr;
    float xr0, xr1, xr2, xc0, xc1, xc2;
    bf16x8 bhr0, bhr1, bhc0, bhc1;
    f32x4 cf0 = zf, cf1 = zf;

    auto issue_gathers = [&](int gg, int rI, int cI) {
        const float* xr = x + (size_t)rI * 3;
        const float* xc = x + (size_t)cI * 3;
        xr0 = xr[0]; xr1 = xr[1]; xr2 = xr[2];
        xc0 = xc[0]; xc1 = xc[1]; xc2 = xc[2];
        const unsigned short* hr = h_bf + (size_t)rI * 64;
        const unsigned short* hc = h_bf + (size_t)cI * 64;
        bhr0 = *(const bf16x8*)(hr + l4 * 8);
        bhr1 = *(const bf16x8*)(hr + 32 + l4 * 8);
        bhc0 = *(const bf16x8*)(hc + l4 * 8);
        bhc1 = *(const bf16x8*)(hc + 32 + l4 * 8);
        if (l4 < 2) {
            const float* fp = edge_fea + (size_t)(gg * 64 + wv * 16 + l15) * 16 + l4 * 8;
            cf0 = *(const f32x4*)fp;
            cf1 = *(const f32x4*)(fp + 4);
        }
    };

    {   // warm-up
        const int e = g * 64 + wv * 16 + l15;
        const int iaR = row[e], iaC = col[e];
        issue_gathers(g, iaR, iaC);
        cr = iaR;
    }
    int ibR = 0, ibC = 0;
    {
        const int gn = g + gstep;
        if (gn < groups) { const int e = gn * 64 + wv * 16 + l15; ibR = row[e]; ibC = col[e]; }
    }

    while (true) {
        const float dx = xr0 - xc0, dy = xr1 - xc1, dz = xr2 - xc2;
        const float sq = dx * dx + dy * dy + dz * dz;

        // fea B-frag via packed converts
        bf16x8 bfea;
        {
            union { unsigned u[4]; bf16x8 v; } cc;
            cc.u[0] = pk2(cf0[0], cf0[1]); cc.u[1] = pk2(cf0[2], cf0[3]);
            cc.u[2] = pk2(cf1[0], cf1[1]); cc.u[3] = pk2(cf1[2], cf1[3]);
            const bf16x8 zv = {0, 0, 0, 0, 0, 0, 0, 0};
            bfea = (l4 < 2) ? cc.v : zv;
        }

        // ---- layer1: acc1 = W1c^T@fea + Wa^T@h_r + Wb^T@h_c
        f32x4 acc1[4];
        #pragma unroll
        for (int t = 0; t < 4; ++t) {
            acc1[t] = __builtin_amdgcn_mfma_f32_16x16x32_bf16(bw1cf[t], bfea, zf, 0, 0, 0);
            acc1[t] = __builtin_amdgcn_mfma_f32_16x16x32_bf16(waf[t][0], bhr0, acc1[t], 0, 0, 0);
            acc1[t] = __builtin_amdgcn_mfma_f32_16x16x32_bf16(waf[t][1], bhr1, acc1[t], 0, 0, 0);
            acc1[t] = __builtin_amdgcn_mfma_f32_16x16x32_bf16(wbf[t][0], bhc0, acc1[t], 0, 0, 0);
            acc1[t] = __builtin_amdgcn_mfma_f32_16x16x32_bf16(wbf[t][1], bhc1, acc1[t], 0, 0, 0);
        }
        #pragma unroll
        for (int t = 0; t < 4; ++t) {
            const f32x4 b1v = cst_s[0][t * 4 + l4];
            const f32x4 w0v = cst_s[1][t * 4 + l4];
            float u0 = silu_f(acc1[t][0] + sq * w0v[0] + b1v[0]);
            float u1 = silu_f(acc1[t][1] + sq * w0v[1] + b1v[1]);
            float u2 = silu_f(acc1[t][2] + sq * w0v[2] + b1v[2]);
            float u3 = silu_f(acc1[t][3] + sq * w0v[3] + b1v[3]);
            uint2 pp; pp.x = pk2(u0, u1); pp.y = pk2(u2, u3);
            *(uint2*)&us[l15 * 72 + t * 16 + l4 * 4] = pp;
        }
        LDS_FENCE();

        // ---- prefetch next group's gathers
        const int gn = g + gstep;
        const bool hn = (gn < groups);
        int nrow = cr;
        if (hn) { issue_gathers(gn, ibR, ibC); nrow = ibR; }

        // ---- layer2 (w2 frags from LDS)
        f32x4 acc2[4];
        {
            const bf16x8 a0 = *(const bf16x8*)&us[l15 * 72 + l4 * 8];
            const bf16x8 a1 = *(const bf16x8*)&us[l15 * 72 + 32 + l4 * 8];
            #pragma unroll
            for (int t = 0; t < 4; ++t) {
                const bf16x8 w0 = *(const bf16x8*)&wlds[(size_t)(t * 2 + 0) * 512 + lane * 8];
                const bf16x8 w1 = *(const bf16x8*)&wlds[(size_t)(t * 2 + 1) * 512 + lane * 8];
                acc2[t] = __builtin_amdgcn_mfma_f32_16x16x32_bf16(w0, a0, zf, 0, 0, 0);
                acc2[t] = __builtin_amdgcn_mfma_f32_16x16x32_bf16(w1, a1, acc2[t], 0, 0, 0);
            }
        }
        LDS_FENCE();
        #pragma unroll
        for (int t = 0; t < 4; ++t) {
            const f32x4 b2v = cst_s[2][t * 4 + l4];
            float m0 = silu_f(acc2[t][0] + b2v[0]);
            float m1 = silu_f(acc2[t][1] + b2v[1]);
            float m2 = silu_f(acc2[t][2] + b2v[2]);
            float m3 = silu_f(acc2[t][3] + b2v[3]);
            uint2 pp; pp.x = pk2(m0, m1); pp.y = pk2(m2, m3);
            *(uint2*)&us[l15 * 72 + t * 16 + l4 * 4] = pp;
        }
        LDS_FENCE();

        // ---- layer3 MFMAs (wc1 frags from LDS; issued before atomics)
        f32x4 acc3[4];
        {
            const bf16x8 a0 = *(const bf16x8*)&us[l15 * 72 + l4 * 8];
            const bf16x8 a1 = *(const bf16x8*)&us[l15 * 72 + 32 + l4 * 8];
            #pragma unroll
            for (int t = 0; t < 4; ++t) {
                const bf16x8 w0 = *(const bf16x8*)&wlds[(size_t)(8 + t * 2 + 0) * 512 + lane * 8];
                const bf16x8 w1 = *(const bf16x8*)&wlds[(size_t)(8 + t * 2 + 1) * 512 + lane * 8];
                acc3[t] = __builtin_amdgcn_mfma_f32_16x16x32_bf16(w0, a0, zf, 0, 0, 0);
                acc3[t] = __builtin_amdgcn_mfma_f32_16x16x32_bf16(w1, a1, acc3[t], 0, 0, 0);
            }
        }

        // ---- tot_msg atomics, packed bf16x2, coalesced (1 line/row/instr)
        #pragma unroll
        for (int r = 0; r < 4; ++r) {
            const int er   = l4 * 4 + r;
            const int rowr = __shfl(cr, er);
            unsigned short* const mb = tot_msg + (size_t)rowr * 64;
            #pragma unroll
            for (int t = 0; t < 2; ++t) {
                const unsigned int pk = *(const unsigned int*)&us[er * 72 + t * 32 + l15 * 2];
                atomic_pk_add_bf16(mb + t * 32 + l15 * 2, pk);
            }
        }

        // ---- coord head
        float p = 0.f;
        #pragma unroll
        for (int t = 0; t < 4; ++t) {
            const f32x4 bcv = cst_s[3][t * 4 + l4];
            const f32x4 wcv = cst_s[4][t * 4 + l4];
            #pragma unroll
            for (int r = 0; r < 4; ++r)
                p += silu_f(acc3[t][r] + bcv[r]) * wcv[r];
        }
        p += __shfl_xor(p, 16);
        p += __shfl_xor(p, 32);
        const float coord = p + bc2v;

        const float comp = (l4 == 0) ? dx : (l4 == 1) ? dy : (l4 == 2) ? dz : 0.f;
        const float val  = (l4 == 3) ? 1.0f : comp * coord;
        atomicAdd(&totf4[(size_t)cr * 4 + l4], val);

        if (!hn) break;
        cr = nrow; g = gn;
        {
            const int g2 = gn + gstep;
            if (g2 < groups) { const int e = g2 * 64 + wv * 16 + l15; ibR = row[e]; ibC = col[e]; }
        }
    }
}

// ---------------------------------------------------------------- K3: nodes
__global__ __launch_bounds__(256, 4) void node_kernel(
    const float* __restrict__ x, const unsigned short* __restrict__ h_bf,
    const unsigned short* __restrict__ wfrag,
    const float* __restrict__ bn1, const float* __restrict__ bn2,
    const unsigned short* __restrict__ tot_msg, const float* __restrict__ totf4,
    float* __restrict__ out)
{
    __shared__ __align__(16) short g_s[4][16 * 72];

    const int tid  = threadIdx.x;
    const int lane = tid & 63;
    const int wv   = __builtin_amdgcn_readfirstlane(tid >> 6);
    const int l15  = lane & 15;
    const int l4   = lane >> 4;

    bf16x8 awn1[4][4], awn2[4][2];
    f32x4 bn1r4[4], bn2r4[4];
    #pragma unroll
    for (int t = 0; t < 4; ++t) {
        #pragma unroll
        for (int s = 0; s < 4; ++s)
            awn1[t][s] = load_frag(wfrag, FR_WN1 + t * 4 + s, lane);
        #pragma unroll
        for (int s = 0; s < 2; ++s)
            awn2[t][s] = load_frag(wfrag, FR_WN2 + t * 2 + s, lane);
        bn1r4[t] = *(const f32x4*)&bn1[t * 16 + l4 * 4];
        bn2r4[t] = *(const f32x4*)&bn2[t * 16 + l4 * 4];
    }

    const f32x4 zf = {0.f, 0.f, 0.f, 0.f};
    const int n_groups = (N_NODES + 63) / 64;
    float* const out_h = out + (size_t)N_NODES * 3;

    for (int g = blockIdx.x; g < n_groups; g += gridDim.x) {
        const int n16  = g * 64 + wv * 16 + l15;
        const int nc   = (n16 < N_NODES) ? n16 : 0;
        const bool valid = (n16 < N_NODES);

        bf16x8 b[4];
        b[0] = *(const bf16x8*)(h_bf + (size_t)nc * 64 + l4 * 8);
        b[1] = *(const bf16x8*)(h_bf + (size_t)nc * 64 + 32 + l4 * 8);
        b[2] = *(const bf16x8*)(tot_msg + (size_t)nc * 64 + l4 * 8);
        b[3] = *(const bf16x8*)(tot_msg + (size_t)nc * 64 + 32 + l4 * 8);

        #pragma unroll
        for (int t = 0; t < 4; ++t) {
            f32x4 acc = __builtin_amdgcn_mfma_f32_16x16x32_bf16(awn1[t][0], b[0], zf, 0, 0, 0);
            acc = __builtin_amdgcn_mfma_f32_16x16x32_bf16(awn1[t][1], b[1], acc, 0, 0, 0);
            acc = __builtin_amdgcn_mfma_f32_16x16x32_bf16(awn1[t][2], b[2], acc, 0, 0, 0);
            acc = __builtin_amdgcn_mfma_f32_16x16x32_bf16(awn1[t][3], b[3], acc, 0, 0, 0);
            float g0 = silu_f(acc[0] + bn1r4[t][0]);
            float g1 = silu_f(acc[1] + bn1r4[t][1]);
            float g2 = silu_f(acc[2] + bn1r4[t][2]);
            float g3 = silu_f(acc[3] + bn1r4[t][3]);
            uint2 pp; pp.x = pk2(g0, g1); pp.y = pk2(g2, g3);
            *(uint2*)&g_s[wv][l15 * 72 + t * 16 + l4 * 4] = pp;
        }
        LDS_FENCE();

        {
            const bf16x8 g0 = *(const bf16x8*)&g_s[wv][l15 * 72 + l4 * 8];
            const bf16x8 g1 = *(const bf16x8*)&g_s[wv][l15 * 72 + 32 + l4 * 8];
            #pragma unroll
            for (int t = 0; t < 4; ++t) {
                f32x4 acc = __builtin_amdgcn_mfma_f32_16x16x32_bf16(awn2[t][0], g0, zf, 0, 0, 0);
                acc = __builtin_amdgcn_mfma_f32_16x16x32_bf16(awn2[t][1], g1, acc, 0, 0, 0);
                if (valid) {
                    f32x4 o;
                    #pragma unroll
                    for (int r = 0; r < 4; ++r) o[r] = acc[r] + bn2r4[t][r];
                    *(f32x4*)&out_h[(size_t)n16 * 64 + t * 16 + l4 * 4] = o;
                }
            }
        }
        LDS_FENCE();

        if (lane < 48) {
            const int nn = lane / 3;
            const int ci = lane % 3;
            const int n  = g * 64 + wv * 16 + nn;
            if (n < N_NODES) {
                const float tot = totf4[n * 4 + ci];
                const float deg = totf4[n * 4 + 3];
                float v = tot / fmaxf(deg, 1.0f);
                v = fminf(fmaxf(v, -100.0f), 100.0f);
                out[n * 3 + ci] = x[n * 3 + ci] + v;
            }
        }
    }
}

// ---------------------------------------------------------------- launcher
extern "C" void kernel_launch(void* const* d_in, const int* in_sizes, int n_in,
                              void* d_out, int out_size, void* d_ws, size_t ws_size,
                              hipStream_t stream) {
    const float* x        = (const float*)d_in[0];
    const float* h        = (const float*)d_in[1];
    const float* edge_fea = (const float*)d_in[2];
    const float* w1e      = (const float*)d_in[3];
    const float* b1e      = (const float*)d_in[4];
    const float* w2e      = (const float*)d_in[5];
    const float* b2e      = (const float*)d_in[6];
    const float* wc1      = (const float*)d_in[7];
    const float* bc1      = (const float*)d_in[8];
    const float* wc2      = (const float*)d_in[9];
    const float* bc2      = (const float*)d_in[10];
    const float* wn1      = (const float*)d_in[11];
    const float* bn1      = (const float*)d_in[12];
    const float* wn2      = (const float*)d_in[13];
    const float* bn2      = (const float*)d_in[14];
    const int*   row      = (const int*)d_in[15];
    const int*   col      = (const int*)d_in[16];
    float* out = (float*)d_out;

    // ws layout: totf4 f32[N*4] | tot_msg bf16[N*64] | h_bf bf16[N*64]
    //            | wfrag bf16[60*512]
    float* totf4 = (float*)d_ws;
    unsigned short* tot_msg = (unsigned short*)(totf4 + (size_t)N_NODES * 4);
    unsigned short* h_bf    = tot_msg + (size_t)N_NODES * 64;
    unsigned short* wfrag   = h_bf + (size_t)N_NODES * 64;

    prep_kernel<<<1024, 256, 0, stream>>>(w1e, w2e, wc1, wn1, wn2, h,
                                          wfrag, h_bf, tot_msg, totf4);
    edge_kernel<<<2500, 256, 0, stream>>>(x, edge_fea, w1e, b1e, b2e, bc1, wc2, bc2,
                                          row, col, h_bf, wfrag, tot_msg, totf4);
    node_kernel<<<782, 256, 0, stream>>>(x, h_bf, wfrag, bn1, bn2, tot_msg, totf4, out);
}